// Round 1
// baseline (509.489 us; speedup 1.0000x reference)
//
#include <hip/hip_runtime.h>

#define B_  16
#define IC  128
#define OC  256
#define ZD  256
#define HH  64
#define WW  64
#define FAN 1152      // IC*3*3
#define NO  294912    // OC*FAN
#define HP  66        // padded H/W

typedef float    fvec4 __attribute__((ext_vector_type(4)));
typedef _Float16 f16x8 __attribute__((ext_vector_type(8)));
typedef _Float16 f16x4 __attribute__((ext_vector_type(4)));

// async global->LDS, 16B/lane: lane i of the wave deposits at ldst + i*16B.
__device__ __forceinline__ void gl_lds16(const _Float16* g, _Float16* ldst) {
  __builtin_amdgcn_global_load_lds(
      (const __attribute__((address_space(1))) unsigned int*)(const void*)g,
      (__attribute__((address_space(3))) unsigned int*)(void*)ldst,
      16, 0, 0);
}

// raw barrier + counted waits (T4): never drain vmcnt to 0 in the main loop.
#define BARRIER()  asm volatile("s_barrier" ::: "memory")
#define WAITVM8()  asm volatile("s_waitcnt vmcnt(8)" ::: "memory")
#define WAITVM4()  asm volatile("s_waitcnt vmcnt(4)" ::: "memory")
#define WAITVM0()  asm volatile("s_waitcnt vmcnt(0)" ::: "memory")
#define WAITLGKM() asm volatile("s_waitcnt lgkmcnt(0)" ::: "memory")

// ---------------------------------------------------------------------------
// Kernel A: delta[b][o] = sum_z z[b][z] * head_w[o][z]  via f16 MFMA.
// (unchanged — HBM-stream-bound at the 302 MB head_w floor)
// ---------------------------------------------------------------------------
__global__ __launch_bounds__(256) void delta_gemm_kernel(
    const float* __restrict__ z, const float* __restrict__ head_w,
    float* __restrict__ delta) {
  __shared__ _Float16 As[256 * 72];     // [row][64 k + 8 pad]
  __shared__ _Float16 zsh[16 * 264];    // [b][256 k + 8 pad]
  int t = threadIdx.x;
  int row0 = blockIdx.x * 256;
  int lane = t & 63, wave = t >> 6;
  int quad = lane >> 4, l16 = lane & 15;

  for (int u = t; u < 1024; u += 256) {
    int b = u >> 6, kq = u & 63;
    fvec4 v = *(const fvec4*)&z[b * 256 + kq * 4];
    f16x4 h = {(_Float16)v.x, (_Float16)v.y, (_Float16)v.z, (_Float16)v.w};
    *(f16x4*)&zsh[b * 264 + kq * 4] = h;
  }

  fvec4 acc[4];
#pragma unroll
  for (int i = 0; i < 4; ++i) acc[i] = (fvec4){0.f, 0.f, 0.f, 0.f};

  int srow_lo = t >> 4;
  int sseg = t & 15;

  for (int zc2 = 0; zc2 < 4; ++zc2) {
    __syncthreads();
#pragma unroll
    for (int i = 0; i < 16; ++i) {
      int row = i * 16 + srow_lo;
      fvec4 v = *(const fvec4*)&head_w[(size_t)(row0 + row) * 256 + zc2 * 64 + sseg * 4];
      f16x4 h = {(_Float16)v.x, (_Float16)v.y, (_Float16)v.z, (_Float16)v.w};
      *(f16x4*)&As[row * 72 + sseg * 4] = h;
    }
    __syncthreads();
#pragma unroll
    for (int kc = 0; kc < 2; ++kc) {
      f16x8 bfz = *(const f16x8*)&zsh[l16 * 264 + zc2 * 64 + kc * 32 + quad * 8];
#pragma unroll
      for (int mt = 0; mt < 4; ++mt) {
        f16x8 af = *(const f16x8*)&As[(wave * 64 + mt * 16 + l16) * 72 + kc * 32 + quad * 8];
        acc[mt] = __builtin_amdgcn_mfma_f32_16x16x32_f16(af, bfz, acc[mt], 0, 0, 0);
      }
    }
  }
#pragma unroll
  for (int mt = 0; mt < 4; ++mt) {
    int gr = row0 + wave * 64 + mt * 16 + quad * 4;
#pragma unroll
    for (int r = 0; r < 4; ++r)
      delta[(size_t)l16 * NO + gr + r] = acc[mt][r];
  }
}

// ---------------------------------------------------------------------------
// Kernel B: standardize delta, add base weight, emit f16 permuted weights.
// (unchanged)
// ---------------------------------------------------------------------------
__global__ __launch_bounds__(256) void standardize_kernel(
    const float* __restrict__ delta, const float* __restrict__ base_w,
    _Float16* __restrict__ w_h) {
  int b  = blockIdx.x >> 8;
  int oc = blockIdx.x & 255;
  int tid = threadIdx.x;
  const float* d = delta + (size_t)b * NO + oc * FAN;

  float s = 0.f, s2 = 0.f;
  for (int j = tid; j < FAN; j += 256) { float v = d[j]; s += v; s2 += v * v; }
#pragma unroll
  for (int off = 32; off > 0; off >>= 1) {
    s  += __shfl_down(s, off);
    s2 += __shfl_down(s2, off);
  }
  __shared__ float rs[4], rq[4];
  if ((tid & 63) == 0) { rs[tid >> 6] = s; rq[tid >> 6] = s2; }
  __syncthreads();
  float S  = rs[0] + rs[1] + rs[2] + rs[3];
  float S2 = rq[0] + rq[1] + rq[2] + rq[3];
  const float inv_fan = 1.0f / (float)FAN;
  float mu  = S * inv_fan;
  float var = S2 * inv_fan - mu * mu;
  const float inv_sqrt2 = 0.70710678118654752f;
  float sc = rsqrtf(var + 1e-5f) * sqrtf(2.0f / (float)FAN) * inv_sqrt2;

  const float* bw = base_w + oc * FAN;
  _Float16* wp = w_h + ((size_t)b * OC + oc) * FAN;
  for (int i = tid; i < FAN; i += 256) {
    int ic = i & 127, kk = i >> 7;
    int j = ic * 9 + kk;
    float val = bw[j] * inv_sqrt2 + (d[j] - mu) * sc;
    wp[i] = (_Float16)val;
  }
}

// ---------------------------------------------------------------------------
// Kernel X: x (f32 NCHW) -> x_h (f16 NHWC, zero-padded [16][66][66][128]).
// (unchanged)
// ---------------------------------------------------------------------------
__global__ __launch_bounds__(256) void xpose_kernel(
    const float* __restrict__ x, _Float16* __restrict__ x_h) {
  int yp = blockIdx.x;
  int b  = blockIdx.y;
  int t  = threadIdx.x;
  _Float16* orow = x_h + ((size_t)(b * HP + yp)) * HP * IC;

  if (yp == 0 || yp == HP - 1) {
    fvec4 zz = (fvec4){0.f, 0.f, 0.f, 0.f};
    for (int u = t; u < HP * IC / 8; u += 256)
      ((fvec4*)orow)[u] = zz;
    return;
  }
  int y = yp - 1;
  __shared__ float tile[128 * 65];
#pragma unroll
  for (int i = 0; i < 8; ++i) {
    int F = i * 256 + t;
    int ic = F >> 4, xq = F & 15;
    fvec4 v = *(const fvec4*)&x[(((size_t)b * IC + ic) * HH + y) * WW + xq * 4];
    float* tp = &tile[ic * 65 + xq * 4];
    tp[0] = v.x; tp[1] = v.y; tp[2] = v.z; tp[3] = v.w;
  }
  __syncthreads();
#pragma unroll
  for (int j = 0; j < 4; ++j) {
    int u = j * 256 + t;
    int px = u >> 4, icg = u & 15;
    _Float16 h[8];
#pragma unroll
    for (int c = 0; c < 8; ++c) h[c] = (_Float16)tile[(icg * 8 + c) * 65 + px];
    *(f16x8*)&orow[(px + 1) * IC + icg * 8] = *(f16x8*)h;
  }
  if (t < 32) {
    int side = t >> 4, icg = t & 15;
    fvec4 zz = (fvec4){0.f, 0.f, 0.f, 0.f};
    *(fvec4*)&orow[(side ? (HP - 1) * IC : 0) + icg * 8] = zz;
  }
}

// ---------------------------------------------------------------------------
// Kernel C (REWRITTEN): implicit-GEMM conv, f16 MFMA 16x16x32.
// 256 oc x 256 px tile, BK=32, 4-slot LDS ring (128 KB), distance-3 prefetch
// with counted vmcnt(8) (T4), raw s_barrier (no drain), setprio (T5).
//   - per K-tile (BK=32): A 256x32 f16 = 16 KB, B 16 KB; 4 gl_lds/thread
//   - slot(T) = T&3; during tile T we stage tile T+3 into slot (T-1)&3,
//     freed because: readers of T-1 drain lgkmcnt before barrier(T), and the
//     stage is issued after barrier(T).
//   - per-wave vmcnt(8) before barrier(T) leaves tiles T+1,T+2 (8 instrs)
//     outstanding and forces tile T landed; the barrier publishes it.
//   - XOR swizzle: rows are 4x16B segs; LDS[row][s] holds global seg
//     s ^ f(row), f(row) = ((row ^ (row>>2)) & 3); reads use quad ^ f.
// Grid: (16 px-tiles of 4 image rows, 16 b), 512 threads = 8 waves (2M x 4N).
// ---------------------------------------------------------------------------
__global__ __launch_bounds__(512, 2) void conv_mfma_kernel(
    const _Float16* __restrict__ x_h, const _Float16* __restrict__ w_h,
    float* __restrict__ out) {
  __shared__ __align__(16) _Float16 As[4 * 8192];   // 4 slots x 256x32 f16
  __shared__ __align__(16) _Float16 Bs[4 * 8192];
  const int t = threadIdx.x;
  const int b = blockIdx.y;
  const int y0 = blockIdx.x * 4;            // 4 image rows per px-tile
  const int lane = t & 63, wave = t >> 6;
  const int wm = wave >> 2, wn = wave & 3;  // 2 M-waves x 4 N-waves
  const int quad = lane >> 4, l16 = lane & 15;

  fvec4 acc[8][4];
#pragma unroll
  for (int i = 0; i < 8; ++i)
#pragma unroll
    for (int j = 0; j < 4; ++j) acc[i][j] = (fvec4){0.f, 0.f, 0.f, 0.f};

  // ---- staging source mapping: per gl_lds, lane -> (row = lr, seg = lane&3)
  const int lr  = lane >> 2;                                  // 16 rows/instr
  const int sw2 = (lane & 3) ^ ((lane >> 2) & 3) ^ ((lane >> 4) & 3);

  // A sources: row = oc = wave*32 + i*16 + lr  (whole M=256 in the block)
  const _Float16* apb0 = w_h + ((size_t)(b * OC + wave * 32 + lr)) * FAN + sw2 * 8;
  const _Float16* apb1 = apb0 + (size_t)16 * FAN;
  // B sources: px p = wave*32 + i*16 + lr; y = y0 + (p>>6), x = p&63
  const int p0 = wave * 32 + lr, p1 = p0 + 16;
  const _Float16* bpb0 =
      x_h + (((size_t)(b * HP + y0 + (p0 >> 6))) * HP + (p0 & 63)) * IC + sw2 * 8;
  const _Float16* bpb1 =
      x_h + (((size_t)(b * HP + y0 + (p1 >> 6))) * HP + (p1 & 63)) * IC + sw2 * 8;

  // LDS DMA dest base within a slot (wave-uniform), halves
  const int adst = wave * 32 * 32;

  // ---- fragment read offsets (halves): row stride 32, seg = quad ^ f(row)
  const int xoro = (l16 & 3) ^ ((l16 >> 2) & 3);
  const int aro = (wm * 128 + l16) * 32 + ((quad ^ xoro) << 3);
  const int bro = (wn * 64  + l16) * 32 + ((quad ^ xoro) << 3);

#define STAGE(slot, akoff, bkoff)                                   \
  do {                                                              \
    _Float16* ad = As + (slot) * 8192 + adst;                       \
    _Float16* bd = Bs + (slot) * 8192 + adst;                       \
    gl_lds16(apb0 + (akoff), ad);                                   \
    gl_lds16(apb1 + (akoff), ad + 512);                             \
    gl_lds16(bpb0 + (bkoff), bd);                                   \
    gl_lds16(bpb1 + (bkoff), bd + 512);                             \
  } while (0)

#define COMPUTE(slot)                                               \
  do {                                                              \
    const _Float16* Ab = As + (slot) * 8192;                        \
    const _Float16* Bb = Bs + (slot) * 8192;                        \
    f16x8 bf[4];                                                    \
    _Pragma("unroll")                                               \
    for (int nf = 0; nf < 4; ++nf)                                  \
      bf[nf] = *(const f16x8*)&Bb[bro + nf * 512];                  \
    __builtin_amdgcn_s_setprio(1);                                  \
    _Pragma("unroll")                                               \
    for (int mf = 0; mf < 8; ++mf) {                                \
      f16x8 af = *(const f16x8*)&Ab[aro + mf * 512];                \
      _Pragma("unroll")                                             \
      for (int nf = 0; nf < 4; ++nf)                                \
        acc[mf][nf] =                                               \
            __builtin_amdgcn_mfma_f32_16x16x32_f16(af, bf[nf], acc[mf][nf], 0, 0, 0); \
    }                                                               \
    __builtin_amdgcn_s_setprio(0);                                  \
  } while (0)

  // ---- prologue: stage tiles 0,1,2 (all tap kk=0, chunks 0..2)
  STAGE(0, 0, 0);
  STAGE(1, 32, 32);
  STAGE(2, 64, 64);

  // ---- main loop: tiles T = kk*4 + c; slot = c; stage tile T+3
  for (int kk = 0; kk < 8; ++kk) {
    const int ky  = kk / 3,       kx  = kk % 3;
    const int ky1 = (kk + 1) / 3, kx1 = (kk + 1) % 3;
    const int ka  = kk * 128;
    const int kb  = (ky * HP + kx) * IC;
    const int ka1 = ka + 128;
    const int kb1 = (ky1 * HP + kx1) * IC;
#pragma unroll
    for (int c = 0; c < 4; ++c) {
      WAITLGKM();                 // own reads of tile T-1 fully serviced
      WAITVM8();                  // own stages of tile T landed (T+1,T+2 in flight)
      BARRIER();                  // publish: tile T staged, tile T-1 readers done
      if (c == 0) STAGE(3, ka + 96, kb + 96);                       // tile (kk,3)
      else        STAGE(c - 1, ka1 + (c - 1) * 32, kb1 + (c - 1) * 32); // (kk+1,c-1)
      COMPUTE(c);
    }
  }
  // ---- peel kk = 8 (ky=2,kx=2): tiles 32..35, drain 8 -> 8 -> 4 -> 0
  {
    const int ka = 1024, kb = (2 * HP + 2) * IC;
    WAITLGKM(); WAITVM8(); BARRIER();
    STAGE(3, ka + 96, kb + 96);   // tile 35
    COMPUTE(0);                   // T=32
    WAITLGKM(); WAITVM8(); BARRIER();
    COMPUTE(1);                   // T=33
    WAITLGKM(); WAITVM4(); BARRIER();
    COMPUTE(2);                   // T=34
    WAITLGKM(); WAITVM0(); BARRIER();
    COMPUTE(3);                   // T=35
  }
#undef STAGE
#undef COMPUTE

  // ---- epilogue: D row = oc (quad*4 + r), col = px (l16)
#pragma unroll
  for (int mf = 0; mf < 8; ++mf)
#pragma unroll
    for (int nf = 0; nf < 4; ++nf) {
      int oc = wm * 128 + mf * 16 + quad * 4;
      int pn = wn * 64 + nf * 16 + l16;
      int oy = y0 + (pn >> 6), ox = pn & 63;
      float* op = out + (((size_t)(b * OC + oc) * HH + oy) * WW + ox);
#pragma unroll
      for (int r = 0; r < 4; ++r)
        op[(size_t)r * HH * WW] = acc[mf][nf][r];
    }
}

// ---------------------------------------------------------------------------
extern "C" void kernel_launch(void* const* d_in, const int* in_sizes, int n_in,
                              void* d_out, int out_size, void* d_ws, size_t ws_size,
                              hipStream_t stream) {
  const float* x      = (const float*)d_in[0];  // [16,128,64,64]
  const float* z      = (const float*)d_in[1];  // [16,256]
  const float* base_w = (const float*)d_in[2];  // [256,128,3,3]
  const float* head_w = (const float*)d_in[3];  // [294912,256]
  float* out = (float*)d_out;                   // [16,256,64,64]

  // ws layout (no aliasing; ~46 MB of ~1.2 GB):
  //   [0)        w_h   f16  9.44 MB
  //   [+9.44MB)  delta f32 18.87 MB
  //   [+28.3MB)  x_h   f16 17.84 MB
  _Float16* w_h   = (_Float16*)d_ws;
  float*    delta = (float*)((char*)d_ws + (size_t)B_ * OC * FAN * sizeof(_Float16));
  _Float16* x_h   = (_Float16*)((char*)d_ws + (size_t)B_ * OC * FAN * sizeof(_Float16)
                                            + (size_t)B_ * NO * sizeof(float));

  delta_gemm_kernel<<<NO / 256, 256, 0, stream>>>(z, head_w, delta);
  standardize_kernel<<<B_ * OC, 256, 0, stream>>>(delta, base_w, w_h);
  xpose_kernel<<<dim3(HP, B_), 256, 0, stream>>>(x, x_h);
  conv_mfma_kernel<<<dim3(16, B_), 512, 0, stream>>>(x_h, w_h, out);
}

// Round 2
// 487.647 us; speedup vs baseline: 1.0448x; 1.0448x over previous
//
#include <hip/hip_runtime.h>

#define B_  16
#define IC  128
#define OC  256
#define ZD  256
#define HH  64
#define WW  64
#define FAN 1152      // IC*3*3
#define NO  294912    // OC*FAN
#define HP  66        // padded H/W

typedef float    fvec4 __attribute__((ext_vector_type(4)));
typedef _Float16 f16x8 __attribute__((ext_vector_type(8)));
typedef _Float16 f16x4 __attribute__((ext_vector_type(4)));

// async global->LDS, 16B/lane: lane i of the wave deposits at ldst + i*16B.
__device__ __forceinline__ void gl_lds16(const _Float16* g, _Float16* ldst) {
  __builtin_amdgcn_global_load_lds(
      (const __attribute__((address_space(1))) unsigned int*)(const void*)g,
      (__attribute__((address_space(3))) unsigned int*)(void*)ldst,
      16, 0, 0);
}

// raw barrier + lgkm-only wait: global loads stay in flight across barriers.
#define BARRIER()  asm volatile("s_barrier" ::: "memory")
#define WAITLGKM() asm volatile("s_waitcnt lgkmcnt(0)" ::: "memory")

// ---------------------------------------------------------------------------
// FUSED Kernel A+B: one block per oc.
//   phase 1: stream head_w[oc] (1.18 MB) in 9 x 128-row chunks, dbuf LDS,
//            MFMA 16x16x32 f16 (M=row, N=16 batch, K=256) -> d in 36 VGPR/lane
//   phase 2: per-b mean/var (shfl_xor quad reduce + 8-wave LDS reduce)
//   phase 3: d -> LDS (f32, reusing stage buffers), permuted coalesced f16
//            w_h write: w_h[b][oc][kk*128+ic] = bw/sqrt2 + (d - mu)*sc
// Removes the 38 MB delta round-trip and one kernel launch vs the old chain.
// ---------------------------------------------------------------------------
__global__ __launch_bounds__(512) void delta_std_fused_kernel(
    const float* __restrict__ z, const float* __restrict__ head_w,
    const float* __restrict__ base_w, _Float16* __restrict__ w_h) {
  __shared__ __align__(16) _Float16 As2[2][128 * 264];  // 135168 B stage (dbuf)
  __shared__ _Float16 zsh[16 * 264];                    // 8448 B
  __shared__ float bsh[FAN];                            // 4608 B
  __shared__ float swS[8 * 16], swQ[8 * 16];
  __shared__ float musb[16], scb[16];

  const int t = threadIdx.x;
  const int oc = blockIdx.x;
  const int lane = t & 63, wave = t >> 6;
  const int quad = lane >> 4, l16 = lane & 15;

  // block's head_w slice: rows oc*1152 .. +1151, row-major K=256.
  const float* hw = head_w + (size_t)oc * FAN * ZD;
  // per-thread stream base: load u = i*512 + t -> row = i*8 + wave, colq = lane
  // (each wave-instr reads 1 KB contiguous: perfect coalescing)
  const float* hwp = hw + (size_t)wave * ZD + lane * 4;

  fvec4 rg[16];
#pragma unroll
  for (int i = 0; i < 16; ++i)
    rg[i] = *(const fvec4*)(hwp + (size_t)i * 8 * ZD);

  // z -> zsh f16 [16][264]
  for (int u = t; u < 1024; u += 512) {
    int b = u >> 6, kq = u & 63;
    fvec4 v = *(const fvec4*)&z[b * ZD + kq * 4];
    f16x4 h = {(_Float16)v.x, (_Float16)v.y, (_Float16)v.z, (_Float16)v.w};
    *(f16x4*)&zsh[b * 264 + kq * 4] = h;
  }
  // base_w[oc] -> bsh f32
  for (int u = t; u < FAN; u += 512) bsh[u] = base_w[oc * FAN + u];

  fvec4 dd[9];

#pragma unroll
  for (int c = 0; c < 9; ++c) {
    // cvt + stage chunk c into buf (c&1)
    _Float16* dst = &As2[c & 1][wave * 264 + lane * 4];
#pragma unroll
    for (int i = 0; i < 16; ++i) {
      fvec4 v = rg[i];
      f16x4 h = {(_Float16)v.x, (_Float16)v.y, (_Float16)v.z, (_Float16)v.w};
      *(f16x4*)(dst + i * 8 * 264) = h;
    }
    // issue chunk c+1 loads; they stay in flight across barrier + MFMA
    if (c < 8) {
      const float* src = hwp + (size_t)(c + 1) * 128 * ZD;
#pragma unroll
      for (int i = 0; i < 16; ++i)
        rg[i] = *(const fvec4*)(src + (size_t)i * 8 * ZD);
    }
    WAITLGKM();   // own ds_writes retired (LDS visible to CU after barrier)
    BARRIER();
    // MFMA: wave w owns rows c*128 + w*16 .. +15; full K=256 in 8 steps
    fvec4 a = (fvec4){0.f, 0.f, 0.f, 0.f};
    const _Float16* Ab = &As2[c & 1][(wave * 16 + l16) * 264 + quad * 8];
    const _Float16* Zb = &zsh[l16 * 264 + quad * 8];
#pragma unroll
    for (int kc = 0; kc < 8; ++kc) {
      f16x8 af = *(const f16x8*)(Ab + kc * 32);
      f16x8 bz = *(const f16x8*)(Zb + kc * 32);
      a = __builtin_amdgcn_mfma_f32_16x16x32_f16(af, bz, a, 0, 0, 0);
    }
    dd[c] = a;    // d[j], j = c*128 + wave*16 + quad*4 + r;  b = l16
    WAITLGKM();   // own ds_reads retired before buf reuse
    BARRIER();
  }

  // ---- stats: per-b sums over fan (this lane holds 36 values for b = l16)
  float s = 0.f, s2 = 0.f;
#pragma unroll
  for (int c = 0; c < 9; ++c)
#pragma unroll
    for (int r = 0; r < 4; ++r) { float v = dd[c][r]; s += v; s2 += v * v; }
  s  += __shfl_xor(s, 16);  s  += __shfl_xor(s, 32);
  s2 += __shfl_xor(s2, 16); s2 += __shfl_xor(s2, 32);
  if (lane < 16) { swS[wave * 16 + l16] = s; swQ[wave * 16 + l16] = s2; }
  __syncthreads();
  if (t < 16) {
    float S = 0.f, S2 = 0.f;
#pragma unroll
    for (int w = 0; w < 8; ++w) { S += swS[w * 16 + t]; S2 += swQ[w * 16 + t]; }
    const float inv_fan = 1.0f / (float)FAN;
    float mu  = S * inv_fan;
    float var = S2 * inv_fan - mu * mu;
    const float inv_sqrt2 = 0.70710678118654752f;
    musb[t] = mu;
    scb[t]  = rsqrtf(var + 1e-5f) * sqrtf(2.0f / (float)FAN) * inv_sqrt2;
  }
  __syncthreads();

  // ---- d -> LDS f32 [1152][17] (reuses stage buffers, now free)
  float* dsh = (float*)&As2[0][0];
#pragma unroll
  for (int c = 0; c < 9; ++c) {
    int jb = c * 128 + wave * 16 + quad * 4;
#pragma unroll
    for (int r = 0; r < 4; ++r)
      dsh[(jb + r) * 17 + l16] = dd[c][r];
  }
  __syncthreads();

  // ---- coalesced permuted write: w_h[b][oc][p], p = kk*128+ic, j = ic*9+kk
  const float inv_sqrt2 = 0.70710678118654752f;
  for (int u = t; u < 2304; u += 512) {       // 16 b x 144 f16x8 segs
    int b = u / 144, seg = u % 144;
    int p0 = seg * 8;
    int kk = p0 >> 7, ic0 = p0 & 127;
    float mu = musb[b], sc = scb[b];
    _Float16 h[8];
#pragma unroll
    for (int e = 0; e < 8; ++e) {
      int j = (ic0 + e) * 9 + kk;
      float val = bsh[j] * inv_sqrt2 + (dsh[j * 17 + b] - mu) * sc;
      h[e] = (_Float16)val;
    }
    *(f16x8*)&w_h[((size_t)b * OC + oc) * FAN + p0] = *(f16x8*)h;
  }
}

// ---------------------------------------------------------------------------
// Kernel X: x (f32 NCHW) -> x_h (f16 NHWC, zero-padded [16][66][66][128]).
// (unchanged)
// ---------------------------------------------------------------------------
__global__ __launch_bounds__(256) void xpose_kernel(
    const float* __restrict__ x, _Float16* __restrict__ x_h) {
  int yp = blockIdx.x;
  int b  = blockIdx.y;
  int t  = threadIdx.x;
  _Float16* orow = x_h + ((size_t)(b * HP + yp)) * HP * IC;

  if (yp == 0 || yp == HP - 1) {
    fvec4 zz = (fvec4){0.f, 0.f, 0.f, 0.f};
    for (int u = t; u < HP * IC / 8; u += 256)
      ((fvec4*)orow)[u] = zz;
    return;
  }
  int y = yp - 1;
  __shared__ float tile[128 * 65];
#pragma unroll
  for (int i = 0; i < 8; ++i) {
    int F = i * 256 + t;
    int ic = F >> 4, xq = F & 15;
    fvec4 v = *(const fvec4*)&x[(((size_t)b * IC + ic) * HH + y) * WW + xq * 4];
    float* tp = &tile[ic * 65 + xq * 4];
    tp[0] = v.x; tp[1] = v.y; tp[2] = v.z; tp[3] = v.w;
  }
  __syncthreads();
#pragma unroll
  for (int j = 0; j < 4; ++j) {
    int u = j * 256 + t;
    int px = u >> 4, icg = u & 15;
    _Float16 h[8];
#pragma unroll
    for (int c = 0; c < 8; ++c) h[c] = (_Float16)tile[(icg * 8 + c) * 65 + px];
    *(f16x8*)&orow[(px + 1) * IC + icg * 8] = *(f16x8*)h;
  }
  if (t < 32) {
    int side = t >> 4, icg = t & 15;
    fvec4 zz = (fvec4){0.f, 0.f, 0.f, 0.f};
    *(fvec4*)&orow[(side ? (HP - 1) * IC : 0) + icg * 8] = zz;
  }
}

// ---------------------------------------------------------------------------
// Kernel C: implicit-GEMM conv, f16 MFMA 16x16x32, BK=64.
// (REVERTED to the round-0 proven version: 128x128 tile, gl_lds staging,
//  XOR-swizzled unpadded tiles; grid = (32 px-tiles, 2 oc-tiles, 16 b).)
// ---------------------------------------------------------------------------
__global__ __launch_bounds__(256) void conv_mfma_kernel(
    const _Float16* __restrict__ x_h, const _Float16* __restrict__ w_h,
    float* __restrict__ out) {
  __shared__ __align__(16) _Float16 As[128 * 64];   // 16 KB, slot-swizzled
  __shared__ __align__(16) _Float16 Bs[128 * 64];   // 16 KB, slot-swizzled
  int t = threadIdx.x;
  int b = blockIdx.z;
  int oc0 = blockIdx.y * 128;
  int y0 = blockIdx.x * 2;
  int lane = t & 63, wave = t >> 6;
  int wm = wave >> 1, wn = wave & 1;
  int quad = lane >> 4, l16 = lane & 15;

  fvec4 acc[4][4];
#pragma unroll
  for (int i = 0; i < 4; ++i)
#pragma unroll
    for (int j = 0; j < 4; ++j) acc[i][j] = (fvec4){0.f, 0.f, 0.f, 0.f};

  // ---- staging source mapping (per wave: rows wave*32 .. +31, 8 rows/instr)
  int lrow = lane >> 3;              // row within 8-row group; row&7 == lrow
  int lseg = lane & 7;               // dest 16B slot
  int sw   = lseg ^ lrow;            // swizzled source segment

  // A: 4 per-lane global pointers (n = 0..3)
  const _Float16* apg[4];
#pragma unroll
  for (int n = 0; n < 4; ++n)
    apg[n] = w_h + ((size_t)(b * OC + oc0 + wave * 32 + n * 8 + lrow)) * FAN + sw * 8;

  // B: px = wave*32 + n*8 + lrow -> ry = wave>>1, xoff = (wave&1)*32 + n*8 + lrow
  const _Float16* bpg0 =
      x_h + (((size_t)(b * HP + y0 + (wave >> 1))) * HP + (wave & 1) * 32 + lrow) * IC + sw * 8;
  const _Float16* bpg1 = bpg0 + 16 * IC;   // n = 2,3

  // LDS DMA dest bases (wave-uniform)
  _Float16* adst = As + wave * 32 * 64;
  _Float16* bdst = Bs + wave * 32 * 64;

  // ---- fragment read offsets (elements); row&7 == l16&7 for frag rows
  int s7 = l16 & 7;
  int arow = (wm * 64 + l16) * 64;
  int brow = (wn * 64 + l16) * 64;
  int aoff[2] = { arow + ((0 + quad) ^ s7) * 8, arow + ((4 + quad) ^ s7) * 8 };
  int boff[2] = { brow + ((0 + quad) ^ s7) * 8, brow + ((4 + quad) ^ s7) * 8 };

#pragma unroll
  for (int ky = 0; ky < 3; ++ky) {
#pragma unroll
    for (int kx = 0; kx < 3; ++kx) {
      const int kk = ky * 3 + kx;
      const _Float16* b0k = bpg0 + (ky * HP + kx) * IC;
      const _Float16* b1k = bpg1 + (ky * HP + kx) * IC;
#pragma unroll
      for (int icc = 0; icc < 2; ++icc) {
        __syncthreads();              // previous iteration's readers done
#pragma unroll
        for (int n = 0; n < 4; ++n)
          gl_lds16(apg[n] + kk * 128 + icc * 64, adst + n * 512);
        gl_lds16(b0k + icc * 64,        bdst);
        gl_lds16(b0k + 1024 + icc * 64, bdst + 512);
        gl_lds16(b1k + icc * 64,        bdst + 1024);
        gl_lds16(b1k + 1024 + icc * 64, bdst + 1536);
        __syncthreads();              // drains vmcnt: DMA data visible
#pragma unroll
        for (int ks = 0; ks < 2; ++ks) {
          f16x8 af[4], bf[4];
#pragma unroll
          for (int i = 0; i < 4; ++i)
            af[i] = *(const f16x8*)&As[aoff[ks] + i * 1024];
#pragma unroll
          for (int j = 0; j < 4; ++j)
            bf[j] = *(const f16x8*)&Bs[boff[ks] + j * 1024];
#pragma unroll
          for (int i = 0; i < 4; ++i)
#pragma unroll
            for (int j = 0; j < 4; ++j)
              acc[i][j] = __builtin_amdgcn_mfma_f32_16x16x32_f16(af[i], bf[j], acc[i][j], 0, 0, 0);
        }
      }
    }
  }

  // epilogue (validated): D row = oc (quad*4 + r), col = pixel (l16)
#pragma unroll
  for (int i = 0; i < 4; ++i)
#pragma unroll
    for (int j = 0; j < 4; ++j) {
      int m  = oc0 + wm * 64 + i * 16 + quad * 4;
      int nn = wn * 64 + j * 16 + l16;
      int oy = y0 + (nn >> 6), ox = nn & 63;
      float* op = out + (((size_t)(b * OC + m) * HH + oy) * WW + ox);
#pragma unroll
      for (int r = 0; r < 4; ++r)
        op[(size_t)r * HH * WW] = acc[i][j][r];
    }
}

// ---------------------------------------------------------------------------
extern "C" void kernel_launch(void* const* d_in, const int* in_sizes, int n_in,
                              void* d_out, int out_size, void* d_ws, size_t ws_size,
                              hipStream_t stream) {
  const float* x      = (const float*)d_in[0];  // [16,128,64,64]
  const float* z      = (const float*)d_in[1];  // [16,256]
  const float* base_w = (const float*)d_in[2];  // [256,128,3,3]
  const float* head_w = (const float*)d_in[3];  // [294912,256]
  float* out = (float*)d_out;                   // [16,256,64,64]

  // ws layout (delta round-trip eliminated; ~27 MB of ~1.2 GB):
  //   [0)        w_h  f16  9.44 MB
  //   [+9.44MB)  x_h  f16 17.84 MB
  _Float16* w_h = (_Float16*)d_ws;
  _Float16* x_h = (_Float16*)((char*)d_ws + (size_t)B_ * OC * FAN * sizeof(_Float16));

  delta_std_fused_kernel<<<OC, 512, 0, stream>>>(z, head_w, base_w, w_h);
  xpose_kernel<<<dim3(HP, B_), 256, 0, stream>>>(x, x_h);
  conv_mfma_kernel<<<dim3(32, 2, B_), 256, 0, stream>>>(x_h, w_h, out);
}